// Round 6
// baseline (356.048 us; speedup 1.0000x reference)
//
#include <hip/hip_runtime.h>
#include <math.h>

#define D_MODEL 512
#define STATE_DIM 16
#define MASK_BUCKETS 2048
#define PPB 256              // points per block; divides N=65536 -> one batch per block
#define N_STATE_BLOCKS 16    // 8 batches x 2 halves of D

typedef float v4f __attribute__((ext_vector_type(4)));

__device__ __forceinline__ v4f f4_load(const float* p) { return *(const v4f*)p; }
__device__ __forceinline__ v4f f4_fma(float s, v4f a, v4f b) {
    return (v4f){fmaf(s, a.x, b.x), fmaf(s, a.y, b.y), fmaf(s, a.z, b.z), fmaf(s, a.w, b.w)};
}

// Fused kernel. Blocks [0, N_STATE_BLOCKS) compute the state token (tiny,
// overlaps with the big point blocks instead of serializing after them).
// Blocks [N_STATE_BLOCKS, ...) each process PPB contiguous points of one batch.
// R5 A/B: identical to R4 except output stores are PLAIN (not nontemporal) —
// testing whether the nt flag was capping write drain at ~5 TB/s vs the
// 6.6 TB/s the harness fill kernel achieves with plain stores.
__global__ __launch_bounds__(256) void fused_proj_kernel(
    const float* __restrict__ xyz,
    const float* __restrict__ state,
    const float* __restrict__ rgb,
    const int*   __restrict__ mask_id,
    const float* __restrict__ Wxyz,
    const float* __restrict__ Wrgb,
    const float* __restrict__ rgb_alpha,
    const float* __restrict__ Wg,
    const float* __restrict__ gripper_alpha,
    const float* __restrict__ Ws1,
    const float* __restrict__ bs1,
    const float* __restrict__ Ws2,
    const float* __restrict__ bs2,
    const float* __restrict__ mask_embed,
    float* __restrict__ out,
    long long total_points,
    int n_points)  // N per batch
{
    const int tid = threadIdx.x;

    if (blockIdx.x < N_STATE_BLOCKS) {
        // ---------------- state token path ----------------
        __shared__ float u[D_MODEL];
        const int b    = blockIdx.x >> 1;
        const int half = blockIdx.x & 1;

        #pragma unroll
        for (int r = 0; r < 2; ++r) {
            const int j = tid + r * 256;
            float acc = bs1[j];
            #pragma unroll
            for (int k = 0; k < STATE_DIM; ++k)
                acc = fmaf(state[b * STATE_DIM + k], Ws1[k * D_MODEL + j], acc);
            u[j] = acc / (1.0f + expf(-acc));   // silu
        }
        __syncthreads();

        const int c = half * 256 + tid;
        float acc2 = bs2[c];
        #pragma unroll 8
        for (int k = 0; k < D_MODEL; ++k)
            acc2 = fmaf(u[k], Ws2[k * D_MODEL + c], acc2);

        out[(size_t)total_points * D_MODEL + (size_t)b * D_MODEL + c] = acc2;
        return;
    }

    // ---------------- point path ----------------
    const int d   = (tid & 127) << 2;   // float4 column slice of D=512
    const int sub = tid >> 7;           // point parity within an iter-pair

    const float ra = rgb_alpha[0];
    const float ga = gripper_alpha[0];

    const long long p0 = (long long)(blockIdx.x - N_STATE_BLOCKS) * PPB;
    const int b = (int)(p0 / n_points);

    const float gx = state[b * STATE_DIM + 0];
    const float gy = state[b * STATE_DIM + 1];
    const float gz = state[b * STATE_DIM + 2];

    // fold weights into registers (once per thread)
    v4f G0 = f4_load(&Wg[0 * D_MODEL + d]) * ga;
    v4f G1 = f4_load(&Wg[1 * D_MODEL + d]) * ga;
    v4f G2 = f4_load(&Wg[2 * D_MODEL + d]) * ga;
    v4f G3 = f4_load(&Wg[3 * D_MODEL + d]) * ga;
    v4f Cb = -(G0 * gx + G1 * gy + G2 * gz);       // -ga*(gxyz . Wg[0:3])
    v4f A0 = f4_load(&Wxyz[0 * D_MODEL + d]) + G0;
    v4f A1 = f4_load(&Wxyz[1 * D_MODEL + d]) + G1;
    v4f A2 = f4_load(&Wxyz[2 * D_MODEL + d]) + G2;
    v4f R0 = f4_load(&Wrgb[0 * D_MODEL + d]) * ra;
    v4f R1 = f4_load(&Wrgb[1 * D_MODEL + d]) * ra;
    v4f R2 = f4_load(&Wrgb[2 * D_MODEL + d]) * ra;

    const int iters = PPB / 4;   // 2 points per thread per iter
    for (int i = 0; i < iters; ++i) {
        const long long pa = p0 + (long long)(i << 2) + sub;
        const long long pb = pa + 2;

        // per-point scalars: broadcast loads (same addr across wave, L1-served)
        const float xa = xyz[pa * 3 + 0], ya = xyz[pa * 3 + 1], za = xyz[pa * 3 + 2];
        const float xb = xyz[pb * 3 + 0], yb = xyz[pb * 3 + 1], zb = xyz[pb * 3 + 2];
        const float ra0 = rgb[pa * 3 + 0], ra1 = rgb[pa * 3 + 1], ra2 = rgb[pa * 3 + 2];
        const float rb0 = rgb[pb * 3 + 0], rb1 = rgb[pb * 3 + 1], rb2 = rgb[pb * 3 + 2];
        const int ma = mask_id[pa] & (MASK_BUCKETS - 1);
        const int mb = mask_id[pb] & (MASK_BUCKETS - 1);

        // two gathers in flight (plain loads: keep 4MB table cached)
        const v4f mea = f4_load(&mask_embed[(size_t)ma * D_MODEL + d]);
        const v4f meb = f4_load(&mask_embed[(size_t)mb * D_MODEL + d]);

        const float rxa = xa - gx, rya = ya - gy, rza = za - gz;
        const float rxb = xb - gx, ryb = yb - gy, rzb = zb - gz;
        const float da = sqrtf(rxa * rxa + rya * rya + rza * rza);
        const float db = sqrtf(rxb * rxb + ryb * ryb + rzb * rzb);

        v4f oa = Cb + mea;
        oa = f4_fma(xa,  A0, oa);
        oa = f4_fma(ya,  A1, oa);
        oa = f4_fma(za,  A2, oa);
        oa = f4_fma(ra0, R0, oa);
        oa = f4_fma(ra1, R1, oa);
        oa = f4_fma(ra2, R2, oa);
        oa = f4_fma(da,  G3, oa);

        v4f ob = Cb + meb;
        ob = f4_fma(xb,  A0, ob);
        ob = f4_fma(yb,  A1, ob);
        ob = f4_fma(zb,  A2, ob);
        ob = f4_fma(rb0, R0, ob);
        ob = f4_fma(rb1, R1, ob);
        ob = f4_fma(rb2, R2, ob);
        ob = f4_fma(db,  G3, ob);

        // PLAIN stores (A/B vs R4's nontemporal): join the 6.6 TB/s fill path
        *(v4f*)&out[(size_t)pa * D_MODEL + d] = oa;
        *(v4f*)&out[(size_t)pb * D_MODEL + d] = ob;
    }
}

extern "C" void kernel_launch(void* const* d_in, const int* in_sizes, int n_in,
                              void* d_out, int out_size, void* d_ws, size_t ws_size,
                              hipStream_t stream) {
    const float* xyz           = (const float*)d_in[0];
    const float* state         = (const float*)d_in[1];
    const float* rgb           = (const float*)d_in[2];
    const int*   mask_id       = (const int*)  d_in[3];
    const float* Wxyz          = (const float*)d_in[4];
    const float* Wrgb          = (const float*)d_in[5];
    const float* rgb_alpha     = (const float*)d_in[6];
    const float* Wg            = (const float*)d_in[7];
    const float* gripper_alpha = (const float*)d_in[8];
    const float* Ws1           = (const float*)d_in[9];
    const float* bs1           = (const float*)d_in[10];
    const float* Ws2           = (const float*)d_in[11];
    const float* bs2           = (const float*)d_in[12];
    const float* mask_embed    = (const float*)d_in[13];
    float* out = (float*)d_out;

    const int B = in_sizes[1] / STATE_DIM;              // 8
    const long long total_points = in_sizes[3];         // B*N = 524288
    const int N = (int)(total_points / B);              // 65536

    const int grid = N_STATE_BLOCKS + (int)(total_points / PPB);  // 16 + 2048

    fused_proj_kernel<<<grid, 256, 0, stream>>>(
        xyz, state, rgb, mask_id, Wxyz, Wrgb, rgb_alpha, Wg, gripper_alpha,
        Ws1, bs1, Ws2, bs2, mask_embed, out, total_points, N);
}

// Round 7
// 214.585 us; speedup vs baseline: 1.6592x; 1.6592x over previous
//
#include <hip/hip_runtime.h>
#include <math.h>

#define D_MODEL 512
#define STATE_DIM 16
#define MASK_BUCKETS 2048
#define PPB 256              // points per block; divides N=65536 -> one batch per block
#define N_STATE_BLOCKS 16    // 8 batches x 2 halves of D

typedef float v4f __attribute__((ext_vector_type(4)));
typedef int   v4i __attribute__((ext_vector_type(4)));

__device__ __forceinline__ v4f f4_load(const float* p) { return *(const v4f*)p; }
__device__ __forceinline__ v4f f4_fma(float s, v4f a, v4f b) {
    return (v4f){fmaf(s, a.x, b.x), fmaf(s, a.y, b.y), fmaf(s, a.z, b.z), fmaf(s, a.w, b.w)};
}

// Blocks [0,16): state token (overlapped). Blocks [16,...): 256 points each.
// R6: all per-point scalars staged once per block via vectorized loads
// (7 wide VMEM instrs instead of ~3584 broadcast scalars), then the inner
// loop is pure {LDS broadcast reads + gather + NT store}. NT stores kept
// (R5 proved plain stores evict the mask table from L2+L3: 356us).
__global__ __launch_bounds__(256) void fused_proj_kernel(
    const float* __restrict__ xyz,
    const float* __restrict__ state,
    const float* __restrict__ rgb,
    const int*   __restrict__ mask_id,
    const float* __restrict__ Wxyz,
    const float* __restrict__ Wrgb,
    const float* __restrict__ rgb_alpha,
    const float* __restrict__ Wg,
    const float* __restrict__ gripper_alpha,
    const float* __restrict__ Ws1,
    const float* __restrict__ bs1,
    const float* __restrict__ Ws2,
    const float* __restrict__ bs2,
    const float* __restrict__ mask_embed,
    float* __restrict__ out,
    long long total_points,
    int n_points)  // N per batch
{
    const int tid = threadIdx.x;

    if (blockIdx.x < N_STATE_BLOCKS) {
        // ---------------- state token path ----------------
        __shared__ float u[D_MODEL];
        const int b    = blockIdx.x >> 1;
        const int half = blockIdx.x & 1;

        #pragma unroll
        for (int r = 0; r < 2; ++r) {
            const int j = tid + r * 256;
            float acc = bs1[j];
            #pragma unroll
            for (int k = 0; k < STATE_DIM; ++k)
                acc = fmaf(state[b * STATE_DIM + k], Ws1[k * D_MODEL + j], acc);
            u[j] = acc / (1.0f + expf(-acc));   // silu
        }
        __syncthreads();

        const int c = half * 256 + tid;
        float acc2 = bs2[c];
        #pragma unroll 8
        for (int k = 0; k < D_MODEL; ++k)
            acc2 = fmaf(u[k], Ws2[k * D_MODEL + c], acc2);

        out[(size_t)total_points * D_MODEL + (size_t)b * D_MODEL + c] = acc2;
        return;
    }

    // ---------------- point path ----------------
    __shared__ float sXYZ[3 * PPB];   // raw staged xyz (3 KB)
    __shared__ float sRGB[3 * PPB];   // raw staged rgb (3 KB)
    __shared__ int   sM[PPB];         // raw staged mask ids (1 KB)
    __shared__ v4f   sA[PPB];         // packed {x, y, z, dist} (4 KB)
    __shared__ v4f   sB[PPB];         // packed {r0, r1, r2, bitcast(m)} (4 KB)

    const int d   = (tid & 127) << 2;   // float4 column slice of D=512
    const int sub = tid >> 7;           // point parity within an iter-pair

    const float ra = rgb_alpha[0];
    const float ga = gripper_alpha[0];

    const long long p0 = (long long)(blockIdx.x - N_STATE_BLOCKS) * PPB;
    const int b = (int)(p0 / n_points);

    const float gx = state[b * STATE_DIM + 0];
    const float gy = state[b * STATE_DIM + 1];
    const float gz = state[b * STATE_DIM + 2];

    // --- phase A: vectorized raw staging (NT: stream-once inputs) ---
    // xyz/rgb block slices: 256 pts * 3 floats = 768 floats = 192 float4 each.
    // mask slice: 256 ints = 64 int4.  16B alignment: p0*12 and p0*4 are
    // multiples of 3072/1024 bytes respectively.
    if (tid < 192) {
        ((v4f*)sXYZ)[tid] = __builtin_nontemporal_load((const v4f*)(xyz + p0 * 3) + tid);
        ((v4f*)sRGB)[tid] = __builtin_nontemporal_load((const v4f*)(rgb + p0 * 3) + tid);
    } else {
        const int t = tid - 192;
        ((v4i*)sM)[t] = __builtin_nontemporal_load((const v4i*)(mask_id + p0) + t);
    }

    // fold weights into registers while staging loads are in flight
    v4f G0 = f4_load(&Wg[0 * D_MODEL + d]) * ga;
    v4f G1 = f4_load(&Wg[1 * D_MODEL + d]) * ga;
    v4f G2 = f4_load(&Wg[2 * D_MODEL + d]) * ga;
    v4f G3 = f4_load(&Wg[3 * D_MODEL + d]) * ga;
    v4f Cb = -(G0 * gx + G1 * gy + G2 * gz);       // -ga*(gxyz . Wg[0:3])
    v4f A0 = f4_load(&Wxyz[0 * D_MODEL + d]) + G0;
    v4f A1 = f4_load(&Wxyz[1 * D_MODEL + d]) + G1;
    v4f A2 = f4_load(&Wxyz[2 * D_MODEL + d]) + G2;
    v4f R0 = f4_load(&Wrgb[0 * D_MODEL + d]) * ra;
    v4f R1 = f4_load(&Wrgb[1 * D_MODEL + d]) * ra;
    v4f R2 = f4_load(&Wrgb[2 * D_MODEL + d]) * ra;

    __syncthreads();

    // --- phase B: pack per-point scalars, dist computed ONCE per point ---
    // stride-3 LDS reads = 2 lanes/bank = conflict-free (m136).
    {
        const float x = sXYZ[3 * tid + 0];
        const float y = sXYZ[3 * tid + 1];
        const float z = sXYZ[3 * tid + 2];
        const float rx = x - gx, ry = y - gy, rz = z - gz;
        const float dist = sqrtf(rx * rx + ry * ry + rz * rz);
        sA[tid] = (v4f){x, y, z, dist};
        sB[tid] = (v4f){sRGB[3 * tid + 0], sRGB[3 * tid + 1], sRGB[3 * tid + 2],
                        __int_as_float(sM[tid] & (MASK_BUCKETS - 1))};
    }
    __syncthreads();

    // --- phase C: inner loop, zero scalar VMEM ---
    #pragma unroll 2
    for (int i = 0; i < PPB / 4; ++i) {
        const int q0 = (i << 2) + sub;
        const int q1 = q0 + 2;

        // broadcast LDS reads (uniform addr per wave -> free)
        const v4f a0 = sA[q0], b0 = sB[q0];
        const v4f a1 = sA[q1], b1 = sB[q1];
        const int m0 = __float_as_int(b0.w);
        const int m1 = __float_as_int(b1.w);

        // gathers from L2-resident table (plain loads)
        const v4f me0 = f4_load(&mask_embed[(size_t)m0 * D_MODEL + d]);
        const v4f me1 = f4_load(&mask_embed[(size_t)m1 * D_MODEL + d]);

        v4f o0 = Cb + me0;
        o0 = f4_fma(a0.x, A0, o0);
        o0 = f4_fma(a0.y, A1, o0);
        o0 = f4_fma(a0.z, A2, o0);
        o0 = f4_fma(b0.x, R0, o0);
        o0 = f4_fma(b0.y, R1, o0);
        o0 = f4_fma(b0.z, R2, o0);
        o0 = f4_fma(a0.w, G3, o0);

        v4f o1 = Cb + me1;
        o1 = f4_fma(a1.x, A0, o1);
        o1 = f4_fma(a1.y, A1, o1);
        o1 = f4_fma(a1.z, A2, o1);
        o1 = f4_fma(b1.x, R0, o1);
        o1 = f4_fma(b1.y, R1, o1);
        o1 = f4_fma(b1.z, R2, o1);
        o1 = f4_fma(a1.w, G3, o1);

        // NT stores: mandatory (R5: plain stores evict table from L2+L3)
        __builtin_nontemporal_store(o0, (v4f*)&out[(size_t)(p0 + q0) * D_MODEL + d]);
        __builtin_nontemporal_store(o1, (v4f*)&out[(size_t)(p0 + q1) * D_MODEL + d]);
    }
}

extern "C" void kernel_launch(void* const* d_in, const int* in_sizes, int n_in,
                              void* d_out, int out_size, void* d_ws, size_t ws_size,
                              hipStream_t stream) {
    const float* xyz           = (const float*)d_in[0];
    const float* state         = (const float*)d_in[1];
    const float* rgb           = (const float*)d_in[2];
    const int*   mask_id       = (const int*)  d_in[3];
    const float* Wxyz          = (const float*)d_in[4];
    const float* Wrgb          = (const float*)d_in[5];
    const float* rgb_alpha     = (const float*)d_in[6];
    const float* Wg            = (const float*)d_in[7];
    const float* gripper_alpha = (const float*)d_in[8];
    const float* Ws1           = (const float*)d_in[9];
    const float* bs1           = (const float*)d_in[10];
    const float* Ws2           = (const float*)d_in[11];
    const float* bs2           = (const float*)d_in[12];
    const float* mask_embed    = (const float*)d_in[13];
    float* out = (float*)d_out;

    const int B = in_sizes[1] / STATE_DIM;              // 8
    const long long total_points = in_sizes[3];         // B*N = 524288
    const int N = (int)(total_points / B);              // 65536

    const int grid = N_STATE_BLOCKS + (int)(total_points / PPB);  // 16 + 2048

    fused_proj_kernel<<<grid, 256, 0, stream>>>(
        xyz, state, rgb, mask_id, Wxyz, Wrgb, rgb_alpha, Wg, gripper_alpha,
        Ws1, bs1, Ws2, bs2, mask_embed, out, total_points, N);
}